// Round 6
// baseline (4940.471 us; speedup 1.0000x reference)
//
#include <hip/hip_runtime.h>
#include <math.h>

typedef unsigned short u16;
typedef unsigned long long u64;
typedef short s16x8 __attribute__((ext_vector_type(8)));
typedef u16 u16x4 __attribute__((ext_vector_type(4)));
typedef float f32x4 __attribute__((ext_vector_type(4)));

#define DEV __device__ __forceinline__

constexpr int B = 64, H = 1152, G4 = 4608, TOUT = 25, TENC = 49;
constexpr unsigned NBLK = 288;

// ---------------- workspace layout (bytes) ----------------
constexpr size_t SZW       = (size_t)G4 * H;                  // big weight elems
constexpr size_t OFF_W     = 0;                               // 7 big bf16 weights
constexpr size_t OFF_WIH0P = OFF_W + 7 * SZW * 2;             // Wih0 padded [4608][64] bf16
constexpr size_t OFF_WHT   = OFF_WIH0P + (size_t)G4 * 64 * 2; // head W^T [5][16][1152] bf16
constexpr size_t OFF_BIAS  = OFF_WHT + (size_t)5 * 16 * H * 2;// [4][4608] f32 (bih+bhh)
constexpr size_t OFF_H     = OFF_BIAS + (size_t)4 * G4 * 4;   // 2 bufs x 6 cells x B*H bf16
constexpr size_t HBUF      = (size_t)6 * B * H * 2;
constexpr size_t OFF_C     = OFF_H + 2 * HBUF;                // 6 x B*H f32
constexpr size_t OFF_X0    = OFF_C + (size_t)6 * B * H * 4;   // [64][64] f32 (54 used)
constexpr size_t OFF_X0B   = OFF_X0 + (size_t)B * 64 * 4;     // [64][64] bf16 (zero-padded)
constexpr size_t OFF_BAR   = OFF_X0B + (size_t)B * 64 * 2;    // 288 flags, 128B apart

DEV u16 f2bf(float f){ union { float f; unsigned u; } v; v.f = f;
  unsigned r = v.u + 0x7fffu + ((v.u >> 16) & 1u); return (u16)(r >> 16); }
DEV f32x4 mfma16(s16x8 a, s16x8 b, f32x4 c){ return __builtin_amdgcn_mfma_f32_16x16x32_bf16(a, b, c, 0, 0, 0); }
DEV s16x8 ld8(const u16* p){ return *reinterpret_cast<const s16x8*>(p); }
DEV float sigf(float x){ return 1.0f / (1.0f + expf(-x)); }

// ---- coherent (sc0 sc1, write-through / L2-bypass) state accessors ----
DEV s16x8 ald16(const u16* p){            // 16B state read as 2x8B system-scope loads
  union { u64 q[2]; s16x8 v; } u;
  u.q[0] = __hip_atomic_load((const u64*)p,     __ATOMIC_RELAXED, __HIP_MEMORY_SCOPE_SYSTEM);
  u.q[1] = __hip_atomic_load((const u64*)(p+4), __ATOMIC_RELAXED, __HIP_MEMORY_SCOPE_SYSTEM);
  return u.v;
}
DEV void  astore16(u16* p, u16 v){ __hip_atomic_store(p, v, __ATOMIC_RELAXED, __HIP_MEMORY_SCOPE_SYSTEM); }
DEV float aloadf(const float* p){ return __hip_atomic_load(p, __ATOMIC_RELAXED, __HIP_MEMORY_SCOPE_SYSTEM); }
DEV void  astoref(float* p, float v){ __hip_atomic_store(p, v, __ATOMIC_RELAXED, __HIP_MEMORY_SCOPE_SYSTEM); }

DEV u16*   WBF(char* ws, int i){ return (u16*)(ws + OFF_W) + (size_t)i * SZW; }
DEV u16*   HPK(char* ws, int buf, int cell){ return (u16*)(ws + OFF_H + (size_t)buf * HBUF) + (size_t)cell * B * H; }
DEV float* CPK(char* ws, int cell){ return (float*)(ws + OFF_C) + (size_t)cell * B * H; }

// ============ grid barrier: flag array, zero RMW, zero cache-wide fences ============
// Arrive: each wave drains its own VMEM (write-through stores reached L3), then
// block's thread 0 stores generation to a private 128B-spaced flag line.
// Wait: threads 0..287 each poll ONE flag (read-shared lines, fully parallel).
DEV void gridbar(unsigned* flags, unsigned gen){
  asm volatile("s_waitcnt vmcnt(0)" ::: "memory");   // per-wave drain
  __syncthreads();
  if(threadIdx.x == 0)
    __hip_atomic_store(&flags[(size_t)blockIdx.x * 32], gen,
                       __ATOMIC_RELAXED, __HIP_MEMORY_SCOPE_SYSTEM);
  if(threadIdx.x < NBLK){
    const unsigned* f = &flags[(size_t)threadIdx.x * 32];
    while(__hip_atomic_load(f, __ATOMIC_RELAXED, __HIP_MEMORY_SCOPE_SYSTEM) < gen)
      __builtin_amdgcn_s_sleep(1);
  }
  __syncthreads();
}

// ================= prep: weight conversion =================
struct PrepW {
  const float* big[7];   // Whh0, Wih1, Whh1, WihA, WhhA, WihL, WhhL
  const float* wih0;
  const float* wh[5];    // W_leg1, W_leg2, W_spine, W_arm1, W_arm2
  const float* bih[4];
  const float* bhh[4];
};

__global__ __launch_bounds__(256) void k_prepw(char* ws, PrepW pa){
  const int r = blockIdx.y;
  const size_t tid = (size_t)blockIdx.x * 256 + threadIdx.x;
  const size_t stride = (size_t)gridDim.x * 256;
  if(r < 7){
    const float4* src = (const float4*)pa.big[r];
    u16x4* dst = (u16x4*)WBF(ws, r);
    const size_t n4 = SZW / 4;
    for(size_t i = tid; i < n4; i += stride){
      float4 v = src[i];
      u16x4 o = { f2bf(v.x), f2bf(v.y), f2bf(v.z), f2bf(v.w) };
      dst[i] = o;
    }
  } else if(r == 7){
    u16* dst = (u16*)(ws + OFF_WIH0P);
    for(size_t i = tid; i < (size_t)G4 * 64; i += stride){
      int row = (int)(i >> 6), k = (int)(i & 63);
      dst[i] = (k < 54) ? f2bf(pa.wih0[(size_t)row * 54 + k]) : (u16)0;
    }
  } else if(r == 8){
    const int HD[5] = {12,12,12,9,9};
    u16* dst = (u16*)(ws + OFF_WHT);
    for(size_t i = tid; i < (size_t)5 * 16 * H; i += stride){
      int h = (int)(i / (16 * H));
      int rem = (int)(i - (size_t)h * 16 * H);
      int n = rem / H, k = rem % H;
      dst[i] = (n < HD[h]) ? f2bf(pa.wh[h][(size_t)k * HD[h] + n]) : (u16)0;
    }
  } else {
    float* dst = (float*)(ws + OFF_BIAS);
    for(size_t i = tid; i < (size_t)4 * G4; i += stride){
      int tag = (int)(i / G4), j = (int)(i % G4);
      dst[i] = pa.bih[tag][j] + pa.bhh[tag][j];
    }
  }
}

// ================= prep: state init =================
__global__ __launch_bounds__(256) void k_preps(char* ws, const float* hs, const float* cs,
                                               const float* gts, const float* p){
  int idx = blockIdx.x * 256 + threadIdx.x;
  if(idx >= B * H) return;
  if(idx < (int)NBLK)                   // reset barrier flags every call (deterministic)
    ((unsigned*)(ws + OFF_BAR))[(size_t)idx * 32] = 0u;
  int b = idx / H, k = idx % H;
  float sh = 0.f, sc = 0.f;
  for(int t = 0; t < TENC; ++t){
    sh += hs[((size_t)b * TENC + t) * H + k];
    sc += cs[((size_t)b * TENC + t) * H + k];
  }
  float h0 = sh * (1.0f / 49.0f);
  float h1 = (gts[(size_t)b * H + k] + sh) * (1.0f / 50.0f);
  float ci = sc * (1.0f / 49.0f);
  HPK(ws,0,0)[idx] = f2bf(h0);
  HPK(ws,0,1)[idx] = f2bf(h1);
  HPK(ws,0,2)[idx] = 0; HPK(ws,0,3)[idx] = 0; HPK(ws,0,4)[idx] = 0; HPK(ws,0,5)[idx] = 0;
  CPK(ws,0)[idx] = ci; CPK(ws,1)[idx] = ci;
  CPK(ws,2)[idx] = 0.f; CPK(ws,3)[idx] = 0.f; CPK(ws,4)[idx] = 0.f; CPK(ws,5)[idx] = 0.f;
  if(k < 64){
    ((u16*)(ws + OFF_X0B))[b * 64 + k] = (k < 54) ? f2bf(p[(size_t)b * 54 + k]) : (u16)0;
    if(k < 54) ((float*)(ws + OFF_X0))[b * 64 + k] = p[(size_t)b * 54 + k];
  }
}

// ============ persistent-kernel building blocks ============
// 288 blocks x 512 thr; block = (mt, jb) 16-row x 16-col x 4-gate tile.
// 8 waves split K (0-3: Wih quarters, 4-7: Whh quarters); LDS 8-partial
// reduce (stride-5, conflict-free); epilogue r = wave (w<4).
// A (state h): coherent loads PREFETCHED to registers; W: normal cached loads.

template<int N>
DEV void accum_rangeN(f32x4* acc, const u16* A, int ldA, const u16* W, int ldW,
                      int mt, int jb, int l15, int lk, int c0){
  s16x8 a[N];
  const u16* ar = A + (size_t)(mt*16 + l15) * ldA + lk*8 + (size_t)c0*32;
  #pragma unroll
  for(int kk = 0; kk < N; ++kk) a[kk] = ald16(ar + (size_t)kk*32);   // all issued up-front
  const u16* wr = W + (size_t)(jb + l15) * ldW + lk*8 + (size_t)c0*32;
  #pragma unroll
  for(int kk = 0; kk < N; ++kk)
    #pragma unroll
    for(int g = 0; g < 4; ++g)
      acc[g] = mfma16(a[kk], ld8(wr + (size_t)g*H*ldW + (size_t)kk*32), acc[g]);
}

// LDS slot p (=wave), gate g, lane, r:  red[((p*4+g)*64 + lane)*5 + r]
DEV void reduce_epi(float* red, const f32x4* acc, int w, int lane, int l15, int lk,
                    int mt, int jb, const float* bias, float* Cc, u16* Hn){
  __syncthreads();                       // red free (previous consumer done)
  #pragma unroll
  for(int g = 0; g < 4; ++g)
    #pragma unroll
    for(int r = 0; r < 4; ++r)
      red[((w*4+g)*64 + lane)*5 + r] = acc[g][r];
  __syncthreads();
  if(w < 4){
    const int r = w;                     // each wave handles one r
    const int col = jb + l15;
    const int row = mt*16 + lk*4 + r;
    float G[4];
    #pragma unroll
    for(int g = 0; g < 4; ++g){
      float s = bias[(size_t)g*H + col];
      #pragma unroll
      for(int p = 0; p < 8; ++p) s += red[((p*4+g)*64 + lane)*5 + r];
      G[g] = s;
    }
    float co = Cc[(size_t)row*H + col];  // C is block-private: cached
    float cn = sigf(G[1])*co + sigf(G[0])*tanhf(G[2]);
    Cc[(size_t)row*H + col] = cn;
    astore16(&Hn[(size_t)row*H + col], f2bf(sigf(G[3])*tanhf(cn)));
  }
}

DEV void cell_phase(float* red, int w, int lane, int l15, int lk, int mt, int jb,
                    const u16* Ain, const u16* Wih, const u16* Aself, const u16* Whh,
                    const float* bias, float* Cc, u16* Hn){
  const int q = w & 3;
  f32x4 acc[4] = {};
  if(w < 4) accum_rangeN<9>(acc, Ain,   (int)H, Wih, (int)H, mt, jb, l15, lk, q*9);
  else      accum_rangeN<9>(acc, Aself, (int)H, Whh, (int)H, mt, jb, l15, lk, q*9);
  reduce_epi(red, acc, w, lane, l15, lk, mt, jb, bias, Cc, Hn);
}

__global__ __launch_bounds__(512, 4) void k_persist(char* ws, float* out,
    const float* bh0, const float* bh1, const float* bh2, const float* bh3, const float* bh4)
{
  const int w = threadIdx.x >> 6;        // 0..7
  const int lane = threadIdx.x & 63;
  const int l15 = lane & 15, lk = lane >> 4;
  const int bid = blockIdx.x;
  const int mt = bid / 72;
  const int jb = (bid % 72) * 16;

  __shared__ float red[8 * 4 * 64 * 5];  // 40 KiB partial-sum buffer
  unsigned* flags = (unsigned*)(ws + OFF_BAR);

  const float* bias = (const float*)(ws + OFF_BIAS);
  float* x0  = (float*)(ws + OFF_X0);
  u16*   x0b = (u16*)(ws + OFF_X0B);
  const u16* Wx = (const u16*)(ws + OFF_WIH0P);

  for(int t = 0; t < TOUT; ++t){
    const int rp = t & 1;
    const unsigned gbase = (unsigned)t * 6u;

    // ---- phase 1: cell0 = x0@Wih0p + h0@Whh0 ----
    // waves 0-3: Whh0 K-quarters (9 chunks); wave 4: x0 chunk 0; wave 5: x0 chunk 1.
    {
      f32x4 acc[4] = {};
      if(w < 4){
        accum_rangeN<9>(acc, HPK(ws,rp,0), (int)H, WBF(ws,0), (int)H, mt, jb, l15, lk, w*9);
      } else if(w < 6){
        accum_rangeN<1>(acc, x0b, 64, Wx, 64, mt, jb, l15, lk, w - 4);
      }
      reduce_epi(red, acc, w, lane, l15, lk, mt, jb, bias, CPK(ws,0), HPK(ws,rp^1,0));
    }
    gridbar(flags, gbase + 1u);

    // ---- phase 2: cell1 = h0n@Wih1 + h1@Whh1 ----
    cell_phase(red, w, lane, l15, lk, mt, jb,
               HPK(ws,rp^1,0), WBF(ws,1), HPK(ws,rp,1), WBF(ws,2),
               bias + G4, CPK(ws,1), HPK(ws,rp^1,1));
    gridbar(flags, gbase + 2u);

    // ---- phase 3: cells 2 & 3 share xA = h1n@WihA (ih partials reused in slots) ----
    {
      const u16* WihA = WBF(ws,3);
      const u16* WhhA = WBF(ws,4);
      const float* b2 = bias + 2*(size_t)G4;
      const int q = w & 3;
      f32x4 accA[4] = {};
      if(w < 4) accum_rangeN<9>(accA, HPK(ws,rp^1,1), (int)H, WihA, (int)H, mt, jb, l15, lk, q*9);
      else      accum_rangeN<9>(accA, HPK(ws,rp,2),   (int)H, WhhA, (int)H, mt, jb, l15, lk, q*9);
      reduce_epi(red, accA, w, lane, l15, lk, mt, jb, b2, CPK(ws,2), HPK(ws,rp^1,2));
      // cell3: waves 0-3 re-contribute their ih partials; waves 4-7 compute Whh3
      f32x4 acc3[4];
      if(w < 4){
        #pragma unroll
        for(int g = 0; g < 4; ++g) acc3[g] = accA[g];
      } else {
        #pragma unroll
        for(int g = 0; g < 4; ++g) acc3[g] = (f32x4){0.f,0.f,0.f,0.f};
        accum_rangeN<9>(acc3, HPK(ws,rp,3), (int)H, WhhA, (int)H, mt, jb, l15, lk, q*9);
      }
      reduce_epi(red, acc3, w, lane, l15, lk, mt, jb, b2, CPK(ws,3), HPK(ws,rp^1,3));
    }
    gridbar(flags, gbase + 3u);

    // ---- phase 4: cell4 = h3n@WihL + h4@WhhL ----
    cell_phase(red, w, lane, l15, lk, mt, jb,
               HPK(ws,rp^1,3), WBF(ws,5), HPK(ws,rp,4), WBF(ws,6),
               bias + 3*(size_t)G4, CPK(ws,4), HPK(ws,rp^1,4));
    gridbar(flags, gbase + 4u);

    // ---- phase 5: cell5 = h4n@WihL + h5@WhhL ----
    cell_phase(red, w, lane, l15, lk, mt, jb,
               HPK(ws,rp^1,4), WBF(ws,5), HPK(ws,rp,5), WBF(ws,6),
               bias + 3*(size_t)G4, CPK(ws,5), HPK(ws,rp^1,5));
    gridbar(flags, gbase + 5u);

    // ---- phase 6: heads (+x0 update), blocks 0..19 = (head, mth) ----
    if(bid < 20){
      const int head = bid >> 2, mth = bid & 3;
      const int HD = (head < 3) ? 12 : 9;
      const int HOFF = (head < 3) ? head*12 : 36 + (head-3)*9;
      const int HSRC[5] = {2,3,1,4,5};
      const u16* A  = HPK(ws, rp^1, HSRC[head]);
      const u16* Wt = (const u16*)(ws + OFF_WHT) + (size_t)head * 16 * H;
      const float* bh = head==0?bh0 : head==1?bh1 : head==2?bh2 : head==3?bh3 : bh4;
      f32x4 acc = {};
      const int cs = (w*36) >> 3, ce = ((w+1)*36) >> 3;
      const u16* ar = A + (size_t)(mth*16 + l15) * H + lk*8;
      const u16* wr = Wt + (size_t)l15 * H + lk*8;
      for(int kk = cs; kk < ce; ++kk)
        acc = mfma16(ald16(ar + (size_t)kk*32), ld8(wr + (size_t)kk*32), acc);
      __syncthreads();
      #pragma unroll
      for(int r = 0; r < 4; ++r) red[((w*4)*64 + lane)*5 + r] = acc[r];
      __syncthreads();
      if(w == 0 && l15 < HD){
        #pragma unroll
        for(int r = 0; r < 4; ++r){
          const int row = mth*16 + lk*4 + r;
          const int c = HOFF + l15;
          float s = bh[l15] + aloadf(&x0[row*64 + c]);
          #pragma unroll
          for(int p = 0; p < 8; ++p) s += red[((p*4)*64 + lane)*5 + r];
          astoref(&out[((size_t)row*TOUT + t)*54 + c], s);
          astoref(&x0[row*64 + c], s);
          astore16(&x0b[row*64 + c], f2bf(s));
        }
      }
    }
    gridbar(flags, gbase + 6u);
  }
}

// ============================ host ============================
extern "C" void kernel_launch(void* const* d_in, const int* in_sizes, int n_in,
                              void* d_out, int out_size, void* d_ws, size_t ws_size,
                              hipStream_t stream){
  (void)in_sizes; (void)n_in; (void)out_size; (void)ws_size;
  char* ws = (char*)d_ws;
  float* out = (float*)d_out;
  const float* hs  = (const float*)d_in[0];
  const float* cs  = (const float*)d_in[1];
  const float* gts = (const float*)d_in[2];
  const float* p   = (const float*)d_in[3];

  PrepW pa;
  pa.big[0] = (const float*)d_in[5];   // Whh0
  pa.big[1] = (const float*)d_in[8];   // Wih1
  pa.big[2] = (const float*)d_in[9];   // Whh1
  pa.big[3] = (const float*)d_in[12];  // WihA
  pa.big[4] = (const float*)d_in[13];  // WhhA
  pa.big[5] = (const float*)d_in[16];  // WihL
  pa.big[6] = (const float*)d_in[17];  // WhhL
  pa.wih0   = (const float*)d_in[4];
  pa.wh[0]  = (const float*)d_in[22];  // W_leg1
  pa.wh[1]  = (const float*)d_in[24];  // W_leg2
  pa.wh[2]  = (const float*)d_in[20];  // W_spine
  pa.wh[3]  = (const float*)d_in[26];  // W_arm1
  pa.wh[4]  = (const float*)d_in[28];  // W_arm2
  pa.bih[0] = (const float*)d_in[6];  pa.bhh[0] = (const float*)d_in[7];
  pa.bih[1] = (const float*)d_in[10]; pa.bhh[1] = (const float*)d_in[11];
  pa.bih[2] = (const float*)d_in[14]; pa.bhh[2] = (const float*)d_in[15];
  pa.bih[3] = (const float*)d_in[18]; pa.bhh[3] = (const float*)d_in[19];

  hipLaunchKernelGGL(k_prepw, dim3(2048, 10), dim3(256), 0, stream, ws, pa);
  hipLaunchKernelGGL(k_preps, dim3(288), dim3(256), 0, stream, ws, hs, cs, gts, p);

  hipLaunchKernelGGL(k_persist, dim3(NBLK), dim3(512), 0, stream, ws, out,
                     (const float*)d_in[23], (const float*)d_in[25], (const float*)d_in[21],
                     (const float*)d_in[27], (const float*)d_in[29]);
}

// Round 7
// 4777.141 us; speedup vs baseline: 1.0342x; 1.0342x over previous
//
#include <hip/hip_runtime.h>
#include <math.h>

typedef unsigned short u16;
typedef unsigned long long u64;
typedef short s16x8 __attribute__((ext_vector_type(8)));
typedef int   i32x4 __attribute__((ext_vector_type(4)));
typedef u16   u16x4 __attribute__((ext_vector_type(4)));
typedef float f32x4 __attribute__((ext_vector_type(4)));

#define DEV __device__ __forceinline__

constexpr int B = 64, H = 1152, G4 = 4608, TOUT = 25, TENC = 49;
constexpr unsigned NBLK = 288;

// ---------------- workspace layout (bytes) ----------------
constexpr size_t SZW       = (size_t)G4 * H;                  // big weight elems
constexpr size_t OFF_W     = 0;                               // 7 big bf16 weights
constexpr size_t OFF_WIH0P = OFF_W + 7 * SZW * 2;             // Wih0 padded [4608][64] bf16
constexpr size_t OFF_WHT   = OFF_WIH0P + (size_t)G4 * 64 * 2; // head W^T [5][16][1152] bf16
constexpr size_t OFF_BIAS  = OFF_WHT + (size_t)5 * 16 * H * 2;// [4][4608] f32 (bih+bhh)
constexpr size_t OFF_H     = OFF_BIAS + (size_t)4 * G4 * 4;   // 2 bufs x 6 cells x B*H bf16
constexpr size_t HBUF      = (size_t)6 * B * H * 2;
constexpr size_t OFF_C     = OFF_H + 2 * HBUF;                // 6 x B*H f32
constexpr size_t OFF_X0    = OFF_C + (size_t)6 * B * H * 4;   // [64][64] f32 (54 used)
constexpr size_t OFF_X0B   = OFF_X0 + (size_t)B * 64 * 4;     // [64][64] bf16 (zero-padded)
constexpr size_t OFF_BAR   = OFF_X0B + (size_t)B * 64 * 2;    // 288 flags, 128B apart

DEV u16 f2bf(float f){ union { float f; unsigned u; } v; v.f = f;
  unsigned r = v.u + 0x7fffu + ((v.u >> 16) & 1u); return (u16)(r >> 16); }
DEV f32x4 mfma16(s16x8 a, s16x8 b, f32x4 c){ return __builtin_amdgcn_mfma_f32_16x16x32_bf16(a, b, c, 0, 0, 0); }
DEV s16x8 ld8(const u16* p){ return *reinterpret_cast<const s16x8*>(p); }
DEV float sigf(float x){ return 1.0f / (1.0f + expf(-x)); }

// ---- async 16B loads via inline asm (issue now, wait via counted vmcnt) ----
DEV void gls(i32x4& d, const u16* p){   // coherent (sc0 sc1): state reads
  asm volatile("global_load_dwordx4 %0, %1, off sc0 sc1" : "=&v"(d) : "v"(p) : "memory");
}
DEV void gld(i32x4& d, const u16* p){   // cached: weight reads
  asm volatile("global_load_dwordx4 %0, %1, off" : "=&v"(d) : "v"(p) : "memory");
}

// ---- coherent (sc0 sc1) synchronous state accessors (small/cheap paths) ----
DEV s16x8 ald16(const u16* p){
  union { u64 q[2]; s16x8 v; } u;
  u.q[0] = __hip_atomic_load((const u64*)p,     __ATOMIC_RELAXED, __HIP_MEMORY_SCOPE_SYSTEM);
  u.q[1] = __hip_atomic_load((const u64*)(p+4), __ATOMIC_RELAXED, __HIP_MEMORY_SCOPE_SYSTEM);
  return u.v;
}
DEV void  astore16(u16* p, u16 v){ __hip_atomic_store(p, v, __ATOMIC_RELAXED, __HIP_MEMORY_SCOPE_SYSTEM); }
DEV float aloadf(const float* p){ return __hip_atomic_load(p, __ATOMIC_RELAXED, __HIP_MEMORY_SCOPE_SYSTEM); }
DEV void  astoref(float* p, float v){ __hip_atomic_store(p, v, __ATOMIC_RELAXED, __HIP_MEMORY_SCOPE_SYSTEM); }

DEV u16*   WBF(char* ws, int i){ return (u16*)(ws + OFF_W) + (size_t)i * SZW; }
DEV u16*   HPK(char* ws, int buf, int cell){ return (u16*)(ws + OFF_H + (size_t)buf * HBUF) + (size_t)cell * B * H; }
DEV float* CPK(char* ws, int cell){ return (float*)(ws + OFF_C) + (size_t)cell * B * H; }

// ============ grid barrier: flag array, zero RMW, zero cache-wide fences ============
DEV void gridbar(unsigned* flags, unsigned gen){
  asm volatile("s_waitcnt vmcnt(0)" ::: "memory");   // per-wave drain of write-through stores
  __syncthreads();
  if(threadIdx.x == 0)
    __hip_atomic_store(&flags[(size_t)blockIdx.x * 32], gen,
                       __ATOMIC_RELAXED, __HIP_MEMORY_SCOPE_SYSTEM);
  if(threadIdx.x < NBLK){
    const unsigned* f = &flags[(size_t)threadIdx.x * 32];
    while(__hip_atomic_load(f, __ATOMIC_RELAXED, __HIP_MEMORY_SCOPE_SYSTEM) < gen)
      __builtin_amdgcn_s_sleep(1);
  }
  __syncthreads();
}

// ============ software-pipelined 9-chunk K-slice matmul ============
// acc[g] += A[rowblock, k-slice] x W_g[colblock, k-slice], k-slice = 9 chunks of 32.
// Issue: 9 coherent A-loads + 4 W-loads up front; steady state: issue next 4 W,
// s_waitcnt vmcnt(4) (counted, never drain), sched_barrier, 4 MFMA.
// Live regs: 36(A) + 32(W dbuf) + 16(acc) + addr ~ 104 < 128 cap -> no spills.
DEV void mm9_pipe(f32x4* acc, const u16* Ab, const u16* w0, const u16* w1,
                  const u16* w2, const u16* w3){
  i32x4 a[9], wb[2][4];
  #pragma unroll
  for(int kk = 0; kk < 9; ++kk) gls(a[kk], Ab + kk*32);
  gld(wb[0][0], w0); gld(wb[0][1], w1); gld(wb[0][2], w2); gld(wb[0][3], w3);
  #pragma unroll
  for(int kk = 0; kk < 9; ++kk){
    const int cur = kk & 1;
    if(kk < 8){
      const int nxt = cur ^ 1, o = (kk+1)*32;
      gld(wb[nxt][0], w0+o); gld(wb[nxt][1], w1+o); gld(wb[nxt][2], w2+o); gld(wb[nxt][3], w3+o);
      asm volatile("s_waitcnt vmcnt(4)" ::: "memory");
    } else {
      asm volatile("s_waitcnt vmcnt(0)" ::: "memory");
    }
    __builtin_amdgcn_sched_barrier(0);
    #pragma unroll
    for(int g = 0; g < 4; ++g)
      acc[g] = mfma16(__builtin_bit_cast(s16x8, a[kk]),
                      __builtin_bit_cast(s16x8, wb[cur][g]), acc[g]);
  }
}

DEV const u16* arow(const u16* A, int row, int lk, int c0){
  return A + (size_t)row * H + (size_t)c0*32 + lk*8;
}
DEV const u16* wrow(const u16* W, int g, int jb, int l15, int lk, int c0){
  return W + ((size_t)g*H + jb + l15) * (size_t)H + (size_t)c0*32 + lk*8;
}

// ================= prep: weight conversion =================
struct PrepW {
  const float* big[7];   // Whh0, Wih1, Whh1, WihA, WhhA, WihL, WhhL
  const float* wih0;
  const float* wh[5];    // W_leg1, W_leg2, W_spine, W_arm1, W_arm2
  const float* bih[4];
  const float* bhh[4];
};

__global__ __launch_bounds__(256) void k_prepw(char* ws, PrepW pa){
  const int r = blockIdx.y;
  const size_t tid = (size_t)blockIdx.x * 256 + threadIdx.x;
  const size_t stride = (size_t)gridDim.x * 256;
  if(r < 7){
    const float4* src = (const float4*)pa.big[r];
    u16x4* dst = (u16x4*)WBF(ws, r);
    const size_t n4 = SZW / 4;
    for(size_t i = tid; i < n4; i += stride){
      float4 v = src[i];
      u16x4 o = { f2bf(v.x), f2bf(v.y), f2bf(v.z), f2bf(v.w) };
      dst[i] = o;
    }
  } else if(r == 7){
    u16* dst = (u16*)(ws + OFF_WIH0P);
    for(size_t i = tid; i < (size_t)G4 * 64; i += stride){
      int row = (int)(i >> 6), k = (int)(i & 63);
      dst[i] = (k < 54) ? f2bf(pa.wih0[(size_t)row * 54 + k]) : (u16)0;
    }
  } else if(r == 8){
    const int HD[5] = {12,12,12,9,9};
    u16* dst = (u16*)(ws + OFF_WHT);
    for(size_t i = tid; i < (size_t)5 * 16 * H; i += stride){
      int h = (int)(i / (16 * H));
      int rem = (int)(i - (size_t)h * 16 * H);
      int n = rem / H, k = rem % H;
      dst[i] = (n < HD[h]) ? f2bf(pa.wh[h][(size_t)k * HD[h] + n]) : (u16)0;
    }
  } else {
    float* dst = (float*)(ws + OFF_BIAS);
    for(size_t i = tid; i < (size_t)4 * G4; i += stride){
      int tag = (int)(i / G4), j = (int)(i % G4);
      dst[i] = pa.bih[tag][j] + pa.bhh[tag][j];
    }
  }
}

// ================= prep: state init =================
__global__ __launch_bounds__(256) void k_preps(char* ws, const float* hs, const float* cs,
                                               const float* gts, const float* p){
  int idx = blockIdx.x * 256 + threadIdx.x;
  if(idx >= B * H) return;
  if(idx < (int)NBLK)                   // reset barrier flags every call (deterministic)
    ((unsigned*)(ws + OFF_BAR))[(size_t)idx * 32] = 0u;
  int b = idx / H, k = idx % H;
  float sh = 0.f, sc = 0.f;
  for(int t = 0; t < TENC; ++t){
    sh += hs[((size_t)b * TENC + t) * H + k];
    sc += cs[((size_t)b * TENC + t) * H + k];
  }
  float h0 = sh * (1.0f / 49.0f);
  float h1 = (gts[(size_t)b * H + k] + sh) * (1.0f / 50.0f);
  float ci = sc * (1.0f / 49.0f);
  HPK(ws,0,0)[idx] = f2bf(h0);
  HPK(ws,0,1)[idx] = f2bf(h1);
  HPK(ws,0,2)[idx] = 0; HPK(ws,0,3)[idx] = 0; HPK(ws,0,4)[idx] = 0; HPK(ws,0,5)[idx] = 0;
  CPK(ws,0)[idx] = ci; CPK(ws,1)[idx] = ci;
  CPK(ws,2)[idx] = 0.f; CPK(ws,3)[idx] = 0.f; CPK(ws,4)[idx] = 0.f; CPK(ws,5)[idx] = 0.f;
  if(k < 64){
    ((u16*)(ws + OFF_X0B))[b * 64 + k] = (k < 54) ? f2bf(p[(size_t)b * 54 + k]) : (u16)0;
    if(k < 54) ((float*)(ws + OFF_X0))[b * 64 + k] = p[(size_t)b * 54 + k];
  }
}

// ============ persistent kernel ============
// 288 blocks x 512 thr; block = (mt, jb) 16-row x 16-col x 4-gate tile.
// 8 waves split K (0-3: Wih quarters, 4-7: Whh quarters); LDS 8-partial
// reduce (stride-5, conflict-free); epilogue r = wave (w<4).

template<int N>
DEV void accum_rangeN(f32x4* acc, const u16* A, int ldA, const u16* W, int ldW,
                      int mt, int jb, int l15, int lk, int c0){
  s16x8 a[N];
  const u16* ar = A + (size_t)(mt*16 + l15) * ldA + lk*8 + (size_t)c0*32;
  #pragma unroll
  for(int kk = 0; kk < N; ++kk) a[kk] = ald16(ar + (size_t)kk*32);
  const u16* wr = W + (size_t)(jb + l15) * ldW + lk*8 + (size_t)c0*32;
  #pragma unroll
  for(int kk = 0; kk < N; ++kk)
    #pragma unroll
    for(int g = 0; g < 4; ++g)
      acc[g] = mfma16(a[kk], ld8(wr + (size_t)g*H*ldW + (size_t)kk*32), acc[g]);
}

// LDS slot p (=wave), gate g, lane, r:  red[((p*4+g)*64 + lane)*5 + r]
DEV void reduce_epi(float* red, const f32x4* acc, int w, int lane, int l15, int lk,
                    int mt, int jb, const float* bias, float* Cc, u16* Hn){
  __syncthreads();                       // red free (previous consumer done)
  #pragma unroll
  for(int g = 0; g < 4; ++g)
    #pragma unroll
    for(int r = 0; r < 4; ++r)
      red[((w*4+g)*64 + lane)*5 + r] = acc[g][r];
  __syncthreads();
  if(w < 4){
    const int r = w;                     // each wave handles one r
    const int col = jb + l15;
    const int row = mt*16 + lk*4 + r;
    float G[4];
    #pragma unroll
    for(int g = 0; g < 4; ++g){
      float s = bias[(size_t)g*H + col];
      #pragma unroll
      for(int p = 0; p < 8; ++p) s += red[((p*4+g)*64 + lane)*5 + r];
      G[g] = s;
    }
    float co = Cc[(size_t)row*H + col];  // C is block-private: cached
    float cn = sigf(G[1])*co + sigf(G[0])*tanhf(G[2]);
    Cc[(size_t)row*H + col] = cn;
    astore16(&Hn[(size_t)row*H + col], f2bf(sigf(G[3])*tanhf(cn)));
  }
}

DEV void cell_phase(float* red, int w, int lane, int l15, int lk, int mt, int jb,
                    const u16* Ain, const u16* Wih, const u16* Aself, const u16* Whh,
                    const float* bias, float* Cc, u16* Hn){
  const int q = w & 3;
  const int row = mt*16 + l15;
  f32x4 acc[4] = {};
  if(w < 4)
    mm9_pipe(acc, arow(Ain, row, lk, q*9),
             wrow(Wih,0,jb,l15,lk,q*9), wrow(Wih,1,jb,l15,lk,q*9),
             wrow(Wih,2,jb,l15,lk,q*9), wrow(Wih,3,jb,l15,lk,q*9));
  else
    mm9_pipe(acc, arow(Aself, row, lk, q*9),
             wrow(Whh,0,jb,l15,lk,q*9), wrow(Whh,1,jb,l15,lk,q*9),
             wrow(Whh,2,jb,l15,lk,q*9), wrow(Whh,3,jb,l15,lk,q*9));
  reduce_epi(red, acc, w, lane, l15, lk, mt, jb, bias, Cc, Hn);
}

__global__ __launch_bounds__(512, 4) void k_persist(char* ws, float* out,
    const float* bh0, const float* bh1, const float* bh2, const float* bh3, const float* bh4)
{
  const int w = threadIdx.x >> 6;        // 0..7
  const int lane = threadIdx.x & 63;
  const int l15 = lane & 15, lk = lane >> 4;
  const int bid = blockIdx.x;
  const int mt = bid / 72;
  const int jb = (bid % 72) * 16;

  __shared__ float red[8 * 4 * 64 * 5];  // 40 KiB partial-sum buffer
  unsigned* flags = (unsigned*)(ws + OFF_BAR);

  const float* bias = (const float*)(ws + OFF_BIAS);
  float* x0  = (float*)(ws + OFF_X0);
  u16*   x0b = (u16*)(ws + OFF_X0B);
  const u16* Wx = (const u16*)(ws + OFF_WIH0P);

  for(int t = 0; t < TOUT; ++t){
    const int rp = t & 1;
    const unsigned gbase = (unsigned)t * 6u;

    // ---- phase 1: cell0 = x0@Wih0p + h0@Whh0 ----
    // waves 0-3: Whh0 K-quarters (pipelined); waves 4,5: x0 chunks; 6,7 idle.
    {
      f32x4 acc[4] = {};
      if(w < 4){
        mm9_pipe(acc, arow(HPK(ws,rp,0), mt*16 + l15, lk, w*9),
                 wrow(WBF(ws,0),0,jb,l15,lk,w*9), wrow(WBF(ws,0),1,jb,l15,lk,w*9),
                 wrow(WBF(ws,0),2,jb,l15,lk,w*9), wrow(WBF(ws,0),3,jb,l15,lk,w*9));
      } else if(w < 6){
        accum_rangeN<1>(acc, x0b, 64, Wx, 64, mt, jb, l15, lk, w - 4);
      }
      reduce_epi(red, acc, w, lane, l15, lk, mt, jb, bias, CPK(ws,0), HPK(ws,rp^1,0));
    }
    gridbar(flags, gbase + 1u);

    // ---- phase 2: cell1 = h0n@Wih1 + h1@Whh1 ----
    cell_phase(red, w, lane, l15, lk, mt, jb,
               HPK(ws,rp^1,0), WBF(ws,1), HPK(ws,rp,1), WBF(ws,2),
               bias + G4, CPK(ws,1), HPK(ws,rp^1,1));
    gridbar(flags, gbase + 2u);

    // ---- phase 3: cells 2 & 3 share xA = h1n@WihA (ih partials reused in regs) ----
    {
      const u16* WihA = WBF(ws,3);
      const u16* WhhA = WBF(ws,4);
      const float* b2 = bias + 2*(size_t)G4;
      const int q = w & 3;
      f32x4 accA[4] = {};
      if(w < 4)
        mm9_pipe(accA, arow(HPK(ws,rp^1,1), mt*16 + l15, lk, q*9),
                 wrow(WihA,0,jb,l15,lk,q*9), wrow(WihA,1,jb,l15,lk,q*9),
                 wrow(WihA,2,jb,l15,lk,q*9), wrow(WihA,3,jb,l15,lk,q*9));
      else
        mm9_pipe(accA, arow(HPK(ws,rp,2), mt*16 + l15, lk, q*9),
                 wrow(WhhA,0,jb,l15,lk,q*9), wrow(WhhA,1,jb,l15,lk,q*9),
                 wrow(WhhA,2,jb,l15,lk,q*9), wrow(WhhA,3,jb,l15,lk,q*9));
      reduce_epi(red, accA, w, lane, l15, lk, mt, jb, b2, CPK(ws,2), HPK(ws,rp^1,2));
      // cell3: waves 0-3 re-contribute their ih partials; waves 4-7 compute Whh3
      f32x4 acc3[4];
      if(w < 4){
        #pragma unroll
        for(int g = 0; g < 4; ++g) acc3[g] = accA[g];
      } else {
        #pragma unroll
        for(int g = 0; g < 4; ++g) acc3[g] = (f32x4){0.f,0.f,0.f,0.f};
        mm9_pipe(acc3, arow(HPK(ws,rp,3), mt*16 + l15, lk, q*9),
                 wrow(WhhA,0,jb,l15,lk,q*9), wrow(WhhA,1,jb,l15,lk,q*9),
                 wrow(WhhA,2,jb,l15,lk,q*9), wrow(WhhA,3,jb,l15,lk,q*9));
      }
      reduce_epi(red, acc3, w, lane, l15, lk, mt, jb, b2, CPK(ws,3), HPK(ws,rp^1,3));
    }
    gridbar(flags, gbase + 3u);

    // ---- phase 4: cell4 = h3n@WihL + h4@WhhL ----
    cell_phase(red, w, lane, l15, lk, mt, jb,
               HPK(ws,rp^1,3), WBF(ws,5), HPK(ws,rp,4), WBF(ws,6),
               bias + 3*(size_t)G4, CPK(ws,4), HPK(ws,rp^1,4));
    gridbar(flags, gbase + 4u);

    // ---- phase 5: cell5 = h4n@WihL + h5@WhhL ----
    cell_phase(red, w, lane, l15, lk, mt, jb,
               HPK(ws,rp^1,4), WBF(ws,5), HPK(ws,rp,5), WBF(ws,6),
               bias + 3*(size_t)G4, CPK(ws,5), HPK(ws,rp^1,5));
    gridbar(flags, gbase + 5u);

    // ---- phase 6: heads (+x0 update), blocks 0..19 = (head, mth) ----
    if(bid < 20){
      const int head = bid >> 2, mth = bid & 3;
      const int HD = (head < 3) ? 12 : 9;
      const int HOFF = (head < 3) ? head*12 : 36 + (head-3)*9;
      const int HSRC[5] = {2,3,1,4,5};
      const u16* A  = HPK(ws, rp^1, HSRC[head]);
      const u16* Wt = (const u16*)(ws + OFF_WHT) + (size_t)head * 16 * H;
      const float* bh = head==0?bh0 : head==1?bh1 : head==2?bh2 : head==3?bh3 : bh4;
      f32x4 acc = {};
      const int cs = (w*36) >> 3, ce = ((w+1)*36) >> 3;
      const u16* ar = A + (size_t)(mth*16 + l15) * H + lk*8;
      const u16* wr = Wt + (size_t)l15 * H + lk*8;
      for(int kk = cs; kk < ce; ++kk)
        acc = mfma16(ald16(ar + (size_t)kk*32), ld8(wr + (size_t)kk*32), acc);
      __syncthreads();
      #pragma unroll
      for(int r = 0; r < 4; ++r) red[((w*4)*64 + lane)*5 + r] = acc[r];
      __syncthreads();
      if(w == 0 && l15 < HD){
        #pragma unroll
        for(int r = 0; r < 4; ++r){
          const int row = mth*16 + lk*4 + r;
          const int c = HOFF + l15;
          float s = bh[l15] + aloadf(&x0[row*64 + c]);
          #pragma unroll
          for(int p = 0; p < 8; ++p) s += red[((p*4)*64 + lane)*5 + r];
          astoref(&out[((size_t)row*TOUT + t)*54 + c], s);
          astoref(&x0[row*64 + c], s);
          astore16(&x0b[row*64 + c], f2bf(s));
        }
      }
    }
    gridbar(flags, gbase + 6u);
  }
}

// ============================ host ============================
extern "C" void kernel_launch(void* const* d_in, const int* in_sizes, int n_in,
                              void* d_out, int out_size, void* d_ws, size_t ws_size,
                              hipStream_t stream){
  (void)in_sizes; (void)n_in; (void)out_size; (void)ws_size;
  char* ws = (char*)d_ws;
  float* out = (float*)d_out;
  const float* hs  = (const float*)d_in[0];
  const float* cs  = (const float*)d_in[1];
  const float* gts = (const float*)d_in[2];
  const float* p   = (const float*)d_in[3];

  PrepW pa;
  pa.big[0] = (const float*)d_in[5];   // Whh0
  pa.big[1] = (const float*)d_in[8];   // Wih1
  pa.big[2] = (const float*)d_in[9];   // Whh1
  pa.big[3] = (const float*)d_in[12];  // WihA
  pa.big[4] = (const float*)d_in[13];  // WhhA
  pa.big[5] = (const float*)d_in[16];  // WihL
  pa.big[6] = (const float*)d_in[17];  // WhhL
  pa.wih0   = (const float*)d_in[4];
  pa.wh[0]  = (const float*)d_in[22];  // W_leg1
  pa.wh[1]  = (const float*)d_in[24];  // W_leg2
  pa.wh[2]  = (const float*)d_in[20];  // W_spine
  pa.wh[3]  = (const float*)d_in[26];  // W_arm1
  pa.wh[4]  = (const float*)d_in[28];  // W_arm2
  pa.bih[0] = (const float*)d_in[6];  pa.bhh[0] = (const float*)d_in[7];
  pa.bih[1] = (const float*)d_in[10]; pa.bhh[1] = (const float*)d_in[11];
  pa.bih[2] = (const float*)d_in[14]; pa.bhh[2] = (const float*)d_in[15];
  pa.bih[3] = (const float*)d_in[18]; pa.bhh[3] = (const float*)d_in[19];

  hipLaunchKernelGGL(k_prepw, dim3(2048, 10), dim3(256), 0, stream, ws, pa);
  hipLaunchKernelGGL(k_preps, dim3(288), dim3(256), 0, stream, ws, hs, cs, gts, p);

  hipLaunchKernelGGL(k_persist, dim3(NBLK), dim3(512), 0, stream, ws, out,
                     (const float*)d_in[23], (const float*)d_in[25], (const float*)d_in[21],
                     (const float*)d_in[27], (const float*)d_in[29]);
}

// Round 8
// 4659.599 us; speedup vs baseline: 1.0603x; 1.0252x over previous
//
#include <hip/hip_runtime.h>
#include <math.h>

typedef unsigned short u16;
typedef unsigned long long u64;
typedef short s16x8 __attribute__((ext_vector_type(8)));
typedef int   i32x4 __attribute__((ext_vector_type(4)));
typedef u16   u16x4 __attribute__((ext_vector_type(4)));
typedef float f32x4 __attribute__((ext_vector_type(4)));

#define DEV __device__ __forceinline__

constexpr int B = 64, H = 1152, G4 = 4608, TOUT = 25, TENC = 49;
constexpr unsigned NBLK = 288;

// ---------------- workspace layout (bytes) ----------------
constexpr size_t SZW       = (size_t)G4 * H;                  // big weight elems
constexpr size_t OFF_W     = 0;                               // 7 big bf16 weights
constexpr size_t OFF_WIH0P = OFF_W + 7 * SZW * 2;             // Wih0 padded [4608][64] bf16
constexpr size_t OFF_WHT   = OFF_WIH0P + (size_t)G4 * 64 * 2; // head W^T [5][16][1152] bf16
constexpr size_t OFF_BIAS  = OFF_WHT + (size_t)5 * 16 * H * 2;// [4][4608] f32 (bih+bhh)
constexpr size_t OFF_H     = OFF_BIAS + (size_t)4 * G4 * 4;   // 2 bufs x 6 cells x B*H bf16
constexpr size_t HBUF      = (size_t)6 * B * H * 2;
constexpr size_t OFF_C     = OFF_H + 2 * HBUF;                // 6 x B*H f32
constexpr size_t OFF_X0    = OFF_C + (size_t)6 * B * H * 4;   // [64][64] f32 (54 used)
constexpr size_t OFF_X0B   = OFF_X0 + (size_t)B * 64 * 4;     // [64][64] bf16 (zero-padded)
constexpr size_t OFF_BAR   = OFF_X0B + (size_t)B * 64 * 2;    // 288 flags, 128B apart

DEV u16 f2bf(float f){ union { float f; unsigned u; } v; v.f = f;
  unsigned r = v.u + 0x7fffu + ((v.u >> 16) & 1u); return (u16)(r >> 16); }
DEV f32x4 mfma16(s16x8 a, s16x8 b, f32x4 c){ return __builtin_amdgcn_mfma_f32_16x16x32_bf16(a, b, c, 0, 0, 0); }
DEV s16x8 ld8(const u16* p){ return *reinterpret_cast<const s16x8*>(p); }
DEV float sigf(float x){ return 1.0f / (1.0f + expf(-x)); }

// ---- async 16B loads via inline asm (issue now, wait via counted vmcnt) ----
DEV void gls(i32x4& d, const u16* p){   // coherent (sc0 sc1): state reads
  asm volatile("global_load_dwordx4 %0, %1, off sc0 sc1" : "=&v"(d) : "v"(p) : "memory");
}
DEV void gld(i32x4& d, const u16* p){   // cached: weight reads
  asm volatile("global_load_dwordx4 %0, %1, off" : "=&v"(d) : "v"(p) : "memory");
}

// ---- coherent (sc0 sc1) synchronous state accessors (small/cheap paths) ----
DEV s16x8 ald16(const u16* p){
  union { u64 q[2]; s16x8 v; } u;
  u.q[0] = __hip_atomic_load((const u64*)p,     __ATOMIC_RELAXED, __HIP_MEMORY_SCOPE_SYSTEM);
  u.q[1] = __hip_atomic_load((const u64*)(p+4), __ATOMIC_RELAXED, __HIP_MEMORY_SCOPE_SYSTEM);
  return u.v;
}
DEV void  astore16(u16* p, u16 v){ __hip_atomic_store(p, v, __ATOMIC_RELAXED, __HIP_MEMORY_SCOPE_SYSTEM); }
DEV float aloadf(const float* p){ return __hip_atomic_load(p, __ATOMIC_RELAXED, __HIP_MEMORY_SCOPE_SYSTEM); }
DEV void  astoref(float* p, float v){ __hip_atomic_store(p, v, __ATOMIC_RELAXED, __HIP_MEMORY_SCOPE_SYSTEM); }

DEV u16*   WBF(char* ws, int i){ return (u16*)(ws + OFF_W) + (size_t)i * SZW; }
DEV u16*   HPK(char* ws, int buf, int cell){ return (u16*)(ws + OFF_H + (size_t)buf * HBUF) + (size_t)cell * B * H; }
DEV float* CPK(char* ws, int cell){ return (float*)(ws + OFF_C) + (size_t)cell * B * H; }

// ============ grid barrier: flag array, zero RMW, zero cache-wide fences ============
DEV void gridbar(unsigned* flags, unsigned gen){
  asm volatile("s_waitcnt vmcnt(0)" ::: "memory");   // per-wave drain of write-through stores
  __syncthreads();
  if(threadIdx.x == 0)
    __hip_atomic_store(&flags[(size_t)blockIdx.x * 32], gen,
                       __ATOMIC_RELAXED, __HIP_MEMORY_SCOPE_SYSTEM);
  if(threadIdx.x < NBLK){
    const unsigned* f = &flags[(size_t)threadIdx.x * 32];
    while(__hip_atomic_load(f, __ATOMIC_RELAXED, __HIP_MEMORY_SCOPE_SYSTEM) < gen)
      __builtin_amdgcn_s_sleep(1);
  }
  __syncthreads();
}

// ============ software-pipelined N-chunk K-slice matmul ============
// acc[g] += A[k-slice] x W_g[k-slice]; N chunks of 32. All N coherent A-loads
// + chunk0 W up front; steady state: issue next 4 W, s_waitcnt vmcnt(4)
// (counted, never drain), sched_barrier, 4 MFMA.
template<int N>
DEV void mmN_pipe(f32x4* acc, const u16* Ab, const u16* w0, const u16* w1,
                  const u16* w2, const u16* w3){
  i32x4 a[N], wb[2][4];
  #pragma unroll
  for(int kk = 0; kk < N; ++kk) gls(a[kk], Ab + kk*32);
  gld(wb[0][0], w0); gld(wb[0][1], w1); gld(wb[0][2], w2); gld(wb[0][3], w3);
  #pragma unroll
  for(int kk = 0; kk < N; ++kk){
    const int cur = kk & 1;
    if(kk < N-1){
      const int nxt = cur ^ 1, o = (kk+1)*32;
      gld(wb[nxt][0], w0+o); gld(wb[nxt][1], w1+o); gld(wb[nxt][2], w2+o); gld(wb[nxt][3], w3+o);
      asm volatile("s_waitcnt vmcnt(4)" ::: "memory");
    } else {
      asm volatile("s_waitcnt vmcnt(0)" ::: "memory");
    }
    __builtin_amdgcn_sched_barrier(0);
    #pragma unroll
    for(int g = 0; g < 4; ++g)
      acc[g] = mfma16(__builtin_bit_cast(s16x8, a[kk]),
                      __builtin_bit_cast(s16x8, wb[cur][g]), acc[g]);
  }
}

DEV const u16* arow(const u16* A, int row, int lk, int c0){
  return A + (size_t)row * H + (size_t)c0*32 + lk*8;
}
DEV const u16* wrow(const u16* W, int g, int jb, int l15, int lk, int c0){
  return W + ((size_t)g*H + jb + l15) * (size_t)H + (size_t)c0*32 + lk*8;
}

// ================= prep: weight conversion =================
struct PrepW {
  const float* big[7];   // Whh0, Wih1, Whh1, WihA, WhhA, WihL, WhhL
  const float* wih0;
  const float* wh[5];    // W_leg1, W_leg2, W_spine, W_arm1, W_arm2
  const float* bih[4];
  const float* bhh[4];
};

__global__ __launch_bounds__(256) void k_prepw(char* ws, PrepW pa){
  const int r = blockIdx.y;
  const size_t tid = (size_t)blockIdx.x * 256 + threadIdx.x;
  const size_t stride = (size_t)gridDim.x * 256;
  if(r < 7){
    const float4* src = (const float4*)pa.big[r];
    u16x4* dst = (u16x4*)WBF(ws, r);
    const size_t n4 = SZW / 4;
    for(size_t i = tid; i < n4; i += stride){
      float4 v = src[i];
      u16x4 o = { f2bf(v.x), f2bf(v.y), f2bf(v.z), f2bf(v.w) };
      dst[i] = o;
    }
  } else if(r == 7){
    u16* dst = (u16*)(ws + OFF_WIH0P);
    for(size_t i = tid; i < (size_t)G4 * 64; i += stride){
      int row = (int)(i >> 6), k = (int)(i & 63);
      dst[i] = (k < 54) ? f2bf(pa.wih0[(size_t)row * 54 + k]) : (u16)0;
    }
  } else if(r == 8){
    const int HD[5] = {12,12,12,9,9};
    u16* dst = (u16*)(ws + OFF_WHT);
    for(size_t i = tid; i < (size_t)5 * 16 * H; i += stride){
      int h = (int)(i / (16 * H));
      int rem = (int)(i - (size_t)h * 16 * H);
      int n = rem / H, k = rem % H;
      dst[i] = (n < HD[h]) ? f2bf(pa.wh[h][(size_t)k * HD[h] + n]) : (u16)0;
    }
  } else {
    float* dst = (float*)(ws + OFF_BIAS);
    for(size_t i = tid; i < (size_t)4 * G4; i += stride){
      int tag = (int)(i / G4), j = (int)(i % G4);
      dst[i] = pa.bih[tag][j] + pa.bhh[tag][j];
    }
  }
}

// ================= prep: state init =================
__global__ __launch_bounds__(256) void k_preps(char* ws, const float* hs, const float* cs,
                                               const float* gts, const float* p){
  int idx = blockIdx.x * 256 + threadIdx.x;
  if(idx >= B * H) return;
  if(idx < (int)NBLK)                   // reset barrier flags every call (deterministic)
    ((unsigned*)(ws + OFF_BAR))[(size_t)idx * 32] = 0u;
  int b = idx / H, k = idx % H;
  float sh = 0.f, sc = 0.f;
  for(int t = 0; t < TENC; ++t){
    sh += hs[((size_t)b * TENC + t) * H + k];
    sc += cs[((size_t)b * TENC + t) * H + k];
  }
  float h0 = sh * (1.0f / 49.0f);
  float h1 = (gts[(size_t)b * H + k] + sh) * (1.0f / 50.0f);
  float ci = sc * (1.0f / 49.0f);
  HPK(ws,0,0)[idx] = f2bf(h0);
  HPK(ws,0,1)[idx] = f2bf(h1);
  HPK(ws,0,2)[idx] = 0; HPK(ws,0,3)[idx] = 0; HPK(ws,0,4)[idx] = 0; HPK(ws,0,5)[idx] = 0;
  CPK(ws,0)[idx] = ci; CPK(ws,1)[idx] = ci;
  CPK(ws,2)[idx] = 0.f; CPK(ws,3)[idx] = 0.f; CPK(ws,4)[idx] = 0.f; CPK(ws,5)[idx] = 0.f;
  if(k < 64){
    ((u16*)(ws + OFF_X0B))[b * 64 + k] = (k < 54) ? f2bf(p[(size_t)b * 54 + k]) : (u16)0;
    if(k < 54) ((float*)(ws + OFF_X0))[b * 64 + k] = p[(size_t)b * 54 + k];
  }
}

// ============ persistent kernel ============
// 288 blocks x 512 thr; XCD-pinned swizzle: bid = x + 8*m + 32*jg ->
// (mt = m, j = jg*8 + x): the 4 mt-blocks of a jb share XCD x, so the 4x
// W-replication is served by that XCD's L2 (2.65 MB/XCD/phase from L3).
// 8 waves split K; LDS 8-partial reduce (stride-5); epilogue r = wave (w<4).

template<int N>
DEV void accum_rangeN(f32x4* acc, const u16* A, int ldA, const u16* W, int ldW,
                      int mt, int jb, int l15, int lk, int c0){
  s16x8 a[N];
  const u16* ar = A + (size_t)(mt*16 + l15) * ldA + lk*8 + (size_t)c0*32;
  #pragma unroll
  for(int kk = 0; kk < N; ++kk) a[kk] = ald16(ar + (size_t)kk*32);
  const u16* wr = W + (size_t)(jb + l15) * ldW + lk*8 + (size_t)c0*32;
  #pragma unroll
  for(int kk = 0; kk < N; ++kk)
    #pragma unroll
    for(int g = 0; g < 4; ++g)
      acc[g] = mfma16(a[kk], ld8(wr + (size_t)g*H*ldW + (size_t)kk*32), acc[g]);
}

// LDS slot p (=wave), gate g, lane, r:  red[((p*4+g)*64 + lane)*5 + r]
DEV void reduce_epi(float* red, const f32x4* acc, int w, int lane, int l15, int lk,
                    int mt, int jb, const float* bias, float* Cc, u16* Hn){
  __syncthreads();                       // red free (previous consumer done)
  #pragma unroll
  for(int g = 0; g < 4; ++g)
    #pragma unroll
    for(int r = 0; r < 4; ++r)
      red[((w*4+g)*64 + lane)*5 + r] = acc[g][r];
  __syncthreads();
  if(w < 4){
    const int r = w;                     // each wave handles one r
    const int col = jb + l15;
    const int row = mt*16 + lk*4 + r;
    float G[4];
    #pragma unroll
    for(int g = 0; g < 4; ++g){
      float s = bias[(size_t)g*H + col];
      #pragma unroll
      for(int p = 0; p < 8; ++p) s += red[((p*4+g)*64 + lane)*5 + r];
      G[g] = s;
    }
    float co = Cc[(size_t)row*H + col];  // C is block-private: cached
    float cn = sigf(G[1])*co + sigf(G[0])*tanhf(G[2]);
    Cc[(size_t)row*H + col] = cn;
    astore16(&Hn[(size_t)row*H + col], f2bf(sigf(G[3])*tanhf(cn)));
  }
}

DEV void cell_phase(float* red, int w, int lane, int l15, int lk, int mt, int jb,
                    const u16* Ain, const u16* Wih, const u16* Aself, const u16* Whh,
                    const float* bias, float* Cc, u16* Hn){
  const int q = w & 3;
  const int row = mt*16 + l15;
  f32x4 acc[4] = {};
  if(w < 4)
    mmN_pipe<9>(acc, arow(Ain, row, lk, q*9),
             wrow(Wih,0,jb,l15,lk,q*9), wrow(Wih,1,jb,l15,lk,q*9),
             wrow(Wih,2,jb,l15,lk,q*9), wrow(Wih,3,jb,l15,lk,q*9));
  else
    mmN_pipe<9>(acc, arow(Aself, row, lk, q*9),
             wrow(Whh,0,jb,l15,lk,q*9), wrow(Whh,1,jb,l15,lk,q*9),
             wrow(Whh,2,jb,l15,lk,q*9), wrow(Whh,3,jb,l15,lk,q*9));
  reduce_epi(red, acc, w, lane, l15, lk, mt, jb, bias, Cc, Hn);
}

// Whh0 x h0 precompute (36 chunks over 8 waves: 5,5,5,5,4,4,4,4)
DEV void pre_cell0(f32x4* acc, char* ws, const u16* h0, int mt, int jb,
                   int l15, int lk, int w){
  const u16* W0 = WBF(ws, 0);
  const int row = mt*16 + l15;
  if(w < 4){
    const int c0 = w*5;
    mmN_pipe<5>(acc, arow(h0, row, lk, c0),
                wrow(W0,0,jb,l15,lk,c0), wrow(W0,1,jb,l15,lk,c0),
                wrow(W0,2,jb,l15,lk,c0), wrow(W0,3,jb,l15,lk,c0));
  } else {
    const int c0 = 20 + (w-4)*4;
    mmN_pipe<4>(acc, arow(h0, row, lk, c0),
                wrow(W0,0,jb,l15,lk,c0), wrow(W0,1,jb,l15,lk,c0),
                wrow(W0,2,jb,l15,lk,c0), wrow(W0,3,jb,l15,lk,c0));
  }
}

__global__
__attribute__((amdgpu_flat_work_group_size(512, 512)))
__attribute__((amdgpu_waves_per_eu(4, 8)))
void k_persist(char* ws, float* out,
    const float* bh0, const float* bh1, const float* bh2, const float* bh3, const float* bh4)
{
  const int w = threadIdx.x >> 6;        // 0..7
  const int lane = threadIdx.x & 63;
  const int l15 = lane & 15, lk = lane >> 4;
  const int bid = blockIdx.x;
  // XCD-pinned swizzle: 4 mt-blocks of each jb share an XCD (bid%8 assumption)
  const int xcd = bid & 7, rr = bid >> 3;
  const int mt = rr & 3;
  const int jb = ((rr >> 2) * 8 + xcd) * 16;

  __shared__ float red[8 * 4 * 64 * 5];  // 40 KiB partial-sum buffer
  unsigned* flags = (unsigned*)(ws + OFF_BAR);

  const float* bias = (const float*)(ws + OFF_BIAS);
  float* x0  = (float*)(ws + OFF_X0);
  u16*   x0b = (u16*)(ws + OFF_X0B);
  const u16* Wx = (const u16*)(ws + OFF_WIH0P);

  // prologue: Whh0 x h0(init) partials for step 0
  f32x4 acc0[4] = {};
  pre_cell0(acc0, ws, HPK(ws,0,0), mt, jb, l15, lk, w);

  for(int t = 0; t < TOUT; ++t){
    const int rp = t & 1;
    const unsigned gbase = (unsigned)t * 6u;

    // ---- phase 1 (light): finish cell0 = [precomputed Whh0·h0] + x0@Wih0p ----
    if(w == 4 || w == 5)
      accum_rangeN<1>(acc0, x0b, 64, Wx, 64, mt, jb, l15, lk, w - 4);
    reduce_epi(red, acc0, w, lane, l15, lk, mt, jb, bias, CPK(ws,0), HPK(ws,rp^1,0));
    gridbar(flags, gbase + 1u);

    // ---- phase 2: cell1 = h0n@Wih1 + h1@Whh1 ----
    cell_phase(red, w, lane, l15, lk, mt, jb,
               HPK(ws,rp^1,0), WBF(ws,1), HPK(ws,rp,1), WBF(ws,2),
               bias + G4, CPK(ws,1), HPK(ws,rp^1,1));
    gridbar(flags, gbase + 2u);

    // ---- phase 3: cells 2 & 3 share xA = h1n@WihA (ih partials reused in regs) ----
    {
      const u16* WihA = WBF(ws,3);
      const u16* WhhA = WBF(ws,4);
      const float* b2 = bias + 2*(size_t)G4;
      const int q = w & 3;
      const int row = mt*16 + l15;
      f32x4 accA[4] = {};
      if(w < 4)
        mmN_pipe<9>(accA, arow(HPK(ws,rp^1,1), row, lk, q*9),
                 wrow(WihA,0,jb,l15,lk,q*9), wrow(WihA,1,jb,l15,lk,q*9),
                 wrow(WihA,2,jb,l15,lk,q*9), wrow(WihA,3,jb,l15,lk,q*9));
      else
        mmN_pipe<9>(accA, arow(HPK(ws,rp,2), row, lk, q*9),
                 wrow(WhhA,0,jb,l15,lk,q*9), wrow(WhhA,1,jb,l15,lk,q*9),
                 wrow(WhhA,2,jb,l15,lk,q*9), wrow(WhhA,3,jb,l15,lk,q*9));
      reduce_epi(red, accA, w, lane, l15, lk, mt, jb, b2, CPK(ws,2), HPK(ws,rp^1,2));
      // cell3: waves 0-3 re-contribute their ih partials; waves 4-7 compute Whh3
      f32x4 acc3[4];
      if(w < 4){
        #pragma unroll
        for(int g = 0; g < 4; ++g) acc3[g] = accA[g];
      } else {
        #pragma unroll
        for(int g = 0; g < 4; ++g) acc3[g] = (f32x4){0.f,0.f,0.f,0.f};
        mmN_pipe<9>(acc3, arow(HPK(ws,rp,3), row, lk, q*9),
                 wrow(WhhA,0,jb,l15,lk,q*9), wrow(WhhA,1,jb,l15,lk,q*9),
                 wrow(WhhA,2,jb,l15,lk,q*9), wrow(WhhA,3,jb,l15,lk,q*9));
      }
      reduce_epi(red, acc3, w, lane, l15, lk, mt, jb, b2, CPK(ws,3), HPK(ws,rp^1,3));
    }
    gridbar(flags, gbase + 3u);

    // ---- phase 4: cell4 = h3n@WihL + h4@WhhL ----
    cell_phase(red, w, lane, l15, lk, mt, jb,
               HPK(ws,rp^1,3), WBF(ws,5), HPK(ws,rp,4), WBF(ws,6),
               bias + 3*(size_t)G4, CPK(ws,4), HPK(ws,rp^1,4));
    gridbar(flags, gbase + 4u);

    // ---- phase 5: cell5 = h4n@WihL + h5@WhhL ----
    cell_phase(red, w, lane, l15, lk, mt, jb,
               HPK(ws,rp^1,4), WBF(ws,5), HPK(ws,rp,5), WBF(ws,6),
               bias + 3*(size_t)G4, CPK(ws,5), HPK(ws,rp^1,5));
    gridbar(flags, gbase + 5u);

    // ---- phase 6: heads (blocks 0..19) + everyone precomputes Whh0·h0n for t+1 ----
    if(bid < 20){
      const int head = bid >> 2, mth = bid & 3;
      const int HD = (head < 3) ? 12 : 9;
      const int HOFF = (head < 3) ? head*12 : 36 + (head-3)*9;
      const int HSRC[5] = {2,3,1,4,5};
      const u16* A  = HPK(ws, rp^1, HSRC[head]);
      const u16* Wt = (const u16*)(ws + OFF_WHT) + (size_t)head * 16 * H;
      const float* bh = head==0?bh0 : head==1?bh1 : head==2?bh2 : head==3?bh3 : bh4;
      f32x4 acc = {};
      const int cs = (w*36) >> 3, ce = ((w+1)*36) >> 3;
      const u16* ar = A + (size_t)(mth*16 + l15) * H + lk*8;
      const u16* wr = Wt + (size_t)l15 * H + lk*8;
      for(int kk = cs; kk < ce; ++kk)
        acc = mfma16(ald16(ar + (size_t)kk*32), ld8(wr + (size_t)kk*32), acc);
      __syncthreads();
      #pragma unroll
      for(int r = 0; r < 4; ++r) red[((w*4)*64 + lane)*5 + r] = acc[r];
      __syncthreads();
      if(w == 0 && l15 < HD){
        #pragma unroll
        for(int r = 0; r < 4; ++r){
          const int row = mth*16 + lk*4 + r;
          const int c = HOFF + l15;
          float s = bh[l15] + aloadf(&x0[row*64 + c]);
          #pragma unroll
          for(int p = 0; p < 8; ++p) s += red[((p*4)*64 + lane)*5 + r];
          astoref(&out[((size_t)row*TOUT + t)*54 + c], s);
          astoref(&x0[row*64 + c], s);
          astore16(&x0b[row*64 + c], f2bf(s));
        }
      }
    }
    #pragma unroll
    for(int g = 0; g < 4; ++g) acc0[g] = (f32x4){0.f,0.f,0.f,0.f};
    if(t < TOUT-1)
      pre_cell0(acc0, ws, HPK(ws,rp^1,0), mt, jb, l15, lk, w);   // h0(t) ready since P1
    gridbar(flags, gbase + 6u);
  }
}

// ============================ host ============================
extern "C" void kernel_launch(void* const* d_in, const int* in_sizes, int n_in,
                              void* d_out, int out_size, void* d_ws, size_t ws_size,
                              hipStream_t stream){
  (void)in_sizes; (void)n_in; (void)out_size; (void)ws_size;
  char* ws = (char*)d_ws;
  float* out = (float*)d_out;
  const float* hs  = (const float*)d_in[0];
  const float* cs  = (const float*)d_in[1];
  const float* gts = (const float*)d_in[2];
  const float* p   = (const float*)d_in[3];

  PrepW pa;
  pa.big[0] = (const float*)d_in[5];   // Whh0
  pa.big[1] = (const float*)d_in[8];   // Wih1
  pa.big[2] = (const float*)d_in[9];   // Whh1
  pa.big[3] = (const float*)d_in[12];  // WihA
  pa.big[4] = (const float*)d_in[13];  // WhhA
  pa.big[5] = (const float*)d_in[16];  // WihL
  pa.big[6] = (const float*)d_in[17];  // WhhL
  pa.wih0   = (const float*)d_in[4];
  pa.wh[0]  = (const float*)d_in[22];  // W_leg1
  pa.wh[1]  = (const float*)d_in[24];  // W_leg2
  pa.wh[2]  = (const float*)d_in[20];  // W_spine
  pa.wh[3]  = (const float*)d_in[26];  // W_arm1
  pa.wh[4]  = (const float*)d_in[28];  // W_arm2
  pa.bih[0] = (const float*)d_in[6];  pa.bhh[0] = (const float*)d_in[7];
  pa.bih[1] = (const float*)d_in[10]; pa.bhh[1] = (const float*)d_in[11];
  pa.bih[2] = (const float*)d_in[14]; pa.bhh[2] = (const float*)d_in[15];
  pa.bih[3] = (const float*)d_in[18]; pa.bhh[3] = (const float*)d_in[19];

  hipLaunchKernelGGL(k_prepw, dim3(2048, 10), dim3(256), 0, stream, ws, pa);
  hipLaunchKernelGGL(k_preps, dim3(288), dim3(256), 0, stream, ws, hs, cs, gts, p);

  hipLaunchKernelGGL(k_persist, dim3(NBLK), dim3(512), 0, stream, ws, out,
                     (const float*)d_in[23], (const float*)d_in[25], (const float*)d_in[21],
                     (const float*)d_in[27], (const float*)d_in[29]);
}